// Round 1
// baseline (277.783 us; speedup 1.0000x reference)
//
#include <hip/hip_runtime.h>

// Problem constants
#define NB   16
#define CIN  256
#define COUT 256
#define HH   32
#define WW   32
#define HW   1024           // 32*32
#define KK   9
#define CK   2304           // CIN*KK

typedef __bf16 bf16x8 __attribute__((ext_vector_type(8)));
typedef float  f32x4  __attribute__((ext_vector_type(4)));

__device__ __forceinline__ unsigned short f2bf(float f) {
    unsigned int u = __float_as_uint(f);
    u += 0x7FFFu + ((u >> 16) & 1u);          // round-nearest-even
    return (unsigned short)(u >> 16);
}

typedef const __attribute__((address_space(1))) void* gas_ptr;
typedef __attribute__((address_space(3))) void* las_ptr;

__device__ __forceinline__ void async16(const void* g, void* l) {
    __builtin_amdgcn_global_load_lds((gas_ptr)g, (las_ptr)l, 16, 0, 0);
}

// ---------------------------------------------------------------- wconv ----
// weight fp32 [O][C][3][3] -> bf16 [O][CK]  (ck = c*9 + k, natural flat order)
__global__ __launch_bounds__(256) void wconv_kernel(const float4* __restrict__ w,
                                                    uint2* __restrict__ wbf) {
    int i = blockIdx.x * 256 + threadIdx.x;   // 147456 float4's
    float4 v = w[i];
    uint2 r;
    r.x = (unsigned)f2bf(v.x) | ((unsigned)f2bf(v.y) << 16);
    r.y = (unsigned)f2bf(v.z) | ((unsigned)f2bf(v.w) << 16);
    wbf[i] = r;
}

// --------------------------------------------------------------- sample ----
// Build val^T in bf16: valt[n][hw][ck] with ck = c*9 + k.
// grid (4 hw-chunks, 16 c-chunks, 16 n), block 256: thread = one hw, loops 16 c.
__global__ __launch_bounds__(256) void sample_kernel(const float* __restrict__ x,
                                                     const float* __restrict__ off,
                                                     unsigned short* __restrict__ valt) {
    const int hw   = blockIdx.x * 256 + threadIdx.x;
    const int n    = blockIdx.z;
    const int cbeg = blockIdx.y * 16;
    const int h = hw >> 5, w = hw & 31;

    const float* op = off + ((size_t)n * HW + hw) * (2 * KK);

    float wgt[KK][4];
    int   idx[KK][4];
#pragma unroll
    for (int k = 0; k < KK; ++k) {
        float dy = op[2 * k];
        float dx = op[2 * k + 1];
        float py = (float)(h + k / 3 - 1) + dy;
        float px = (float)(w + k % 3 - 1) + dx;
        float y0f = floorf(py), x0f = floorf(px);
        float ly = py - y0f, lx = px - x0f;
        int y0 = (int)y0f, x0 = (int)x0f;
#pragma unroll
        for (int c2 = 0; c2 < 4; ++c2) {
            int yy = y0 + (c2 >> 1);
            int xx = x0 + (c2 & 1);
            float wy = (c2 >> 1) ? ly : 1.0f - ly;
            float wx = (c2 & 1) ? lx : 1.0f - lx;
            bool v = (yy >= 0) && (yy < HH) && (xx >= 0) && (xx < WW);
            wgt[k][c2] = v ? wy * wx : 0.0f;
            int yc = yy < 0 ? 0 : (yy > HH - 1 ? HH - 1 : yy);
            int xc = xx < 0 ? 0 : (xx > WW - 1 ? WW - 1 : xx);
            idx[k][c2] = yc * WW + xc;
        }
    }

    unsigned short* vrow = valt + ((size_t)n * HW + hw) * CK;

    for (int cp = 0; cp < 8; ++cp) {
        int c = cbeg + cp * 2;
        unsigned short tmp[2 * KK];
#pragma unroll
        for (int j = 0; j < 2; ++j) {
            const float* xp = x + (size_t)(n * CIN + c + j) * HW;
#pragma unroll
            for (int k = 0; k < KK; ++k) {
                float a = wgt[k][0] * xp[idx[k][0]] + wgt[k][1] * xp[idx[k][1]]
                        + wgt[k][2] * xp[idx[k][2]] + wgt[k][3] * xp[idx[k][3]];
                tmp[j * KK + k] = f2bf(a);
            }
        }
        // 18 bf16 contiguous at element c*9 (c even -> dword aligned)
        unsigned int* dst = (unsigned int*)(vrow + (size_t)c * KK);
#pragma unroll
        for (int q = 0; q < KK; ++q)
            dst[q] = (unsigned)tmp[2 * q] | ((unsigned)tmp[2 * q + 1] << 16);
    }
}

// ----------------------------------------------------------------- gemm ----
// Per image: out[O=256][HW=1024] = wbf[O][CK] * val[CK][HW]
// A = wbf (row-major [O][CK]), B^T = valt (row-major [HW][CK]).
// Tile BM=64, BN=128, BK=32. 2x2 waves, wave tile 32x64 (2x4 subtiles 16x16).
// grid (4, 8, 16) = 512 blocks, 256 threads.
__global__ __launch_bounds__(256, 2) void gemm_kernel(const unsigned short* __restrict__ wbf,
                                                      const unsigned short* __restrict__ valt,
                                                      float* __restrict__ out) {
    __shared__ unsigned short As[64 * 32];    // [m][k]  rows of 64B
    __shared__ unsigned short Bs[128 * 32];   // [n][k]  rows of 64B

    const int tid  = threadIdx.x;
    const int wv   = tid >> 6;
    const int lane = tid & 63;
    const int quad = lane >> 4;
    const int l15  = lane & 15;
    const int wm   = wv & 1;                  // 0..1 (M direction, 32 each)
    const int wn   = wv >> 1;                 // 0..1 (N direction, 64 each)

    const int o0   = blockIdx.x * 64;
    const int hw0  = blockIdx.y * 128;
    const int nimg = blockIdx.z;

    // staging lane pattern: lane -> row lane/4, ck sub-offset (lane&3)*8
    const int srow = lane >> 2;
    const int sck  = (lane & 3) * 8;

    const unsigned short* Ag = wbf + (size_t)o0 * CK;
    const unsigned short* Bg = valt + ((size_t)nimg * HW + hw0) * CK;

    f32x4 acc[2][4] = {};

    for (int ck0 = 0; ck0 < CK; ck0 += 32) {
        __syncthreads();
        // A: 64 rows x 32 ck = 4KB. Each wave loads 16 rows (1 instr).
        {
            int r = wv * 16 + srow;
            async16(Ag + (size_t)r * CK + ck0 + sck, &As[(wv * 16) * 32]);
        }
        // B: 128 rows x 32 ck = 8KB. Each wave loads 32 rows (2 instrs).
        {
            int r = wv * 32 + srow;
            async16(Bg + (size_t)r * CK + ck0 + sck, &Bs[(wv * 32) * 32]);
            async16(Bg + (size_t)(r + 16) * CK + ck0 + sck, &Bs[(wv * 32 + 16) * 32]);
        }
        __syncthreads();

        bf16x8 af[2], bfr[4];
#pragma unroll
        for (int mi = 0; mi < 2; ++mi)
            af[mi] = *(const bf16x8*)&As[(wm * 32 + mi * 16 + l15) * 32 + quad * 8];
#pragma unroll
        for (int ni = 0; ni < 4; ++ni)
            bfr[ni] = *(const bf16x8*)&Bs[(wn * 64 + ni * 16 + l15) * 32 + quad * 8];
#pragma unroll
        for (int mi = 0; mi < 2; ++mi)
#pragma unroll
            for (int ni = 0; ni < 4; ++ni)
                acc[mi][ni] = __builtin_amdgcn_mfma_f32_16x16x32_bf16(af[mi], bfr[ni], acc[mi][ni], 0, 0, 0);
    }

    // epilogue: D layout col = lane&15, row = quad*4 + reg
    float* opnt = out + ((size_t)nimg * COUT + o0) * HW + hw0;
#pragma unroll
    for (int mi = 0; mi < 2; ++mi) {
#pragma unroll
        for (int ni = 0; ni < 4; ++ni) {
            int col = wn * 64 + ni * 16 + l15;
#pragma unroll
            for (int r = 0; r < 4; ++r) {
                int row = wm * 32 + mi * 16 + quad * 4 + r;
                opnt[(size_t)row * HW + col] = acc[mi][ni][r];
            }
        }
    }
}

// --------------------------------------------------------------- launch ----
extern "C" void kernel_launch(void* const* d_in, const int* in_sizes, int n_in,
                              void* d_out, int out_size, void* d_ws, size_t ws_size,
                              hipStream_t stream) {
    const float* x   = (const float*)d_in[0];   // [16][256][32][32]
    const float* off = (const float*)d_in[1];   // [16][1024][18]
    const float* wt  = (const float*)d_in[2];   // [256][256][3][3]
    float* out = (float*)d_out;                 // [16][256][32][32]

    unsigned short* wbf  = (unsigned short*)d_ws;                        // 256*2304*2 = 1179648 B
    unsigned short* valt = (unsigned short*)((char*)d_ws + 1179648);     // 16*1024*2304*2 = 75497472 B

    wconv_kernel<<<576, 256, 0, stream>>>((const float4*)wt, (uint2*)wbf);
    sample_kernel<<<dim3(4, 16, 16), 256, 0, stream>>>(x, off, valt);
    gemm_kernel<<<dim3(4, 8, 16), 256, 0, stream>>>(wbf, valt, out);
}

// Round 2
// 153.048 us; speedup vs baseline: 1.8150x; 1.8150x over previous
//
#include <hip/hip_runtime.h>

// Problem constants
#define NB   16
#define CIN  256
#define COUT 256
#define HH   32
#define WW   32
#define HW   1024           // 32*32
#define KK   9
#define CK   2304           // CIN*KK

typedef __bf16 bf16x8 __attribute__((ext_vector_type(8)));
typedef float  f32x4  __attribute__((ext_vector_type(4)));

__device__ __forceinline__ unsigned short f2bf(float f) {
    unsigned int u = __float_as_uint(f);
    u += 0x7FFFu + ((u >> 16) & 1u);          // round-nearest-even
    return (unsigned short)(u >> 16);
}

typedef const __attribute__((address_space(1))) void* gas_ptr;
typedef __attribute__((address_space(3))) void* las_ptr;

__device__ __forceinline__ void async16(const void* g, void* l) {
    __builtin_amdgcn_global_load_lds((gas_ptr)g, (las_ptr)l, 16, 0, 0);
}

// ---------------------------------------------------------------- wconv ----
// weight fp32 [O][C][3][3] -> bf16 [O][CK]  (ck = c*9 + k, natural flat order)
__global__ __launch_bounds__(256) void wconv_kernel(const float4* __restrict__ w,
                                                    uint2* __restrict__ wbf) {
    int i = blockIdx.x * 256 + threadIdx.x;   // 147456 float4's
    float4 v = w[i];
    uint2 r;
    r.x = (unsigned)f2bf(v.x) | ((unsigned)f2bf(v.y) << 16);
    r.y = (unsigned)f2bf(v.z) | ((unsigned)f2bf(v.w) << 16);
    wbf[i] = r;
}

// --------------------------------------------------------------- sample ----
// Build val^T in bf16: valt[n][hw][ck] with ck = c*9 + k.
// Block = (8-channel chunk, n). Stage x[n][c0..c0+8][1024] (32 KB) in LDS,
// gather bilinear corners from LDS instead of global.
// grid (32 cchunks, 16 n), 256 threads; each thread does 4 hw x 8 c x 9 k.
__global__ __launch_bounds__(256) void sample_kernel(const float* __restrict__ x,
                                                     const float* __restrict__ off,
                                                     unsigned short* __restrict__ valt) {
    __shared__ float xs[8][HW];               // 32 KB

    const int tid  = threadIdx.x;
    const int lane = tid & 63;
    const int wv   = tid >> 6;
    const int c0   = blockIdx.x * 8;
    const int n    = blockIdx.y;

    // stage 8 channels: 8192 floats = 2048 float4 = 8 chunks of 1KB per wave
    const float4* xg4 = (const float4*)(x + ((size_t)n * CIN + c0) * HW);
#pragma unroll
    for (int j = 0; j < 8; ++j) {
        int chunk = wv * 8 + j;               // 0..31, each 64 lanes x 16B
        async16(xg4 + chunk * 64 + lane, &xs[0][chunk * 256]);
    }
    __syncthreads();

    for (int i = 0; i < 4; ++i) {
        const int hw = i * 256 + tid;
        const int h = hw >> 5, w = hw & 31;

        const float2* op2 = (const float2*)(off + ((size_t)n * HW + hw) * (2 * KK));

        float wgt[KK][4];
        int   idx[KK][4];
#pragma unroll
        for (int k = 0; k < KK; ++k) {
            float2 o = op2[k];
            float py = (float)(h + k / 3 - 1) + o.x;
            float px = (float)(w + k % 3 - 1) + o.y;
            float y0f = floorf(py), x0f = floorf(px);
            float ly = py - y0f, lx = px - x0f;
            int y0 = (int)y0f, x0 = (int)x0f;
#pragma unroll
            for (int c2 = 0; c2 < 4; ++c2) {
                int yy = y0 + (c2 >> 1);
                int xx = x0 + (c2 & 1);
                float wy = (c2 >> 1) ? ly : 1.0f - ly;
                float wx = (c2 & 1) ? lx : 1.0f - lx;
                bool v = (yy >= 0) && (yy < HH) && (xx >= 0) && (xx < WW);
                wgt[k][c2] = v ? wy * wx : 0.0f;
                int yc = yy < 0 ? 0 : (yy > HH - 1 ? HH - 1 : yy);
                int xc = xx < 0 ? 0 : (xx > WW - 1 ? WW - 1 : xx);
                idx[k][c2] = yc * WW + xc;
            }
        }

        unsigned tmp32[36];
#pragma unroll
        for (int c = 0; c < 8; ++c) {
            const float* xp = &xs[c][0];
#pragma unroll
            for (int k = 0; k < KK; ++k) {
                float a = wgt[k][0] * xp[idx[k][0]] + wgt[k][1] * xp[idx[k][1]]
                        + wgt[k][2] * xp[idx[k][2]] + wgt[k][3] * xp[idx[k][3]];
                unsigned short b = f2bf(a);
                int j = c * KK + k;
                if (j & 1) tmp32[j >> 1] |= ((unsigned)b) << 16;
                else       tmp32[j >> 1]  = (unsigned)b;
            }
        }

        // 72 bf16 = 144 B contiguous, 16B-aligned -> 9 dwordx4 stores
        uint4* dst = (uint4*)(valt + ((size_t)n * HW + hw) * CK + (size_t)c0 * KK);
        const uint4* src = (const uint4*)tmp32;
#pragma unroll
        for (int q = 0; q < 9; ++q) dst[q] = src[q];
    }
}

// ----------------------------------------------------------------- gemm ----
// Per image: out[O=256][HW=1024] = wbf[O][CK] * val[CK][HW]
// A = wbf (row-major [O][CK]), B^T = valt (row-major [HW][CK]).
// Tile BM=64, BN=128, BK=32. 2x2 waves, wave tile 32x64 (2x4 subtiles 16x16).
// grid (4, 8, 16) = 512 blocks, 256 threads.
__global__ __launch_bounds__(256, 2) void gemm_kernel(const unsigned short* __restrict__ wbf,
                                                      const unsigned short* __restrict__ valt,
                                                      float* __restrict__ out) {
    __shared__ unsigned short As[64 * 32];    // [m][k]  rows of 64B
    __shared__ unsigned short Bs[128 * 32];   // [n][k]  rows of 64B

    const int tid  = threadIdx.x;
    const int wv   = tid >> 6;
    const int lane = tid & 63;
    const int quad = lane >> 4;
    const int l15  = lane & 15;
    const int wm   = wv & 1;                  // 0..1 (M direction, 32 each)
    const int wn   = wv >> 1;                 // 0..1 (N direction, 64 each)

    const int o0   = blockIdx.x * 64;
    const int hw0  = blockIdx.y * 128;
    const int nimg = blockIdx.z;

    // staging lane pattern: lane -> row lane/4, ck sub-offset (lane&3)*8
    const int srow = lane >> 2;
    const int sck  = (lane & 3) * 8;

    const unsigned short* Ag = wbf + (size_t)o0 * CK;
    const unsigned short* Bg = valt + ((size_t)nimg * HW + hw0) * CK;

    f32x4 acc[2][4] = {};

    for (int ck0 = 0; ck0 < CK; ck0 += 32) {
        __syncthreads();
        // A: 64 rows x 32 ck = 4KB. Each wave loads 16 rows (1 instr).
        {
            int r = wv * 16 + srow;
            async16(Ag + (size_t)r * CK + ck0 + sck, &As[(wv * 16) * 32]);
        }
        // B: 128 rows x 32 ck = 8KB. Each wave loads 32 rows (2 instrs).
        {
            int r = wv * 32 + srow;
            async16(Bg + (size_t)r * CK + ck0 + sck, &Bs[(wv * 32) * 32]);
            async16(Bg + (size_t)(r + 16) * CK + ck0 + sck, &Bs[(wv * 32 + 16) * 32]);
        }
        __syncthreads();

        bf16x8 af[2], bfr[4];
#pragma unroll
        for (int mi = 0; mi < 2; ++mi)
            af[mi] = *(const bf16x8*)&As[(wm * 32 + mi * 16 + l15) * 32 + quad * 8];
#pragma unroll
        for (int ni = 0; ni < 4; ++ni)
            bfr[ni] = *(const bf16x8*)&Bs[(wn * 64 + ni * 16 + l15) * 32 + quad * 8];
#pragma unroll
        for (int mi = 0; mi < 2; ++mi)
#pragma unroll
            for (int ni = 0; ni < 4; ++ni)
                acc[mi][ni] = __builtin_amdgcn_mfma_f32_16x16x32_bf16(af[mi], bfr[ni], acc[mi][ni], 0, 0, 0);
    }

    // epilogue: D layout col = lane&15, row = quad*4 + reg
    float* opnt = out + ((size_t)nimg * COUT + o0) * HW + hw0;
#pragma unroll
    for (int mi = 0; mi < 2; ++mi) {
#pragma unroll
        for (int ni = 0; ni < 4; ++ni) {
            int col = wn * 64 + ni * 16 + l15;
#pragma unroll
            for (int r = 0; r < 4; ++r) {
                int row = wm * 32 + mi * 16 + quad * 4 + r;
                opnt[(size_t)row * HW + col] = acc[mi][ni][r];
            }
        }
    }
}

// --------------------------------------------------------------- launch ----
extern "C" void kernel_launch(void* const* d_in, const int* in_sizes, int n_in,
                              void* d_out, int out_size, void* d_ws, size_t ws_size,
                              hipStream_t stream) {
    const float* x   = (const float*)d_in[0];   // [16][256][32][32]
    const float* off = (const float*)d_in[1];   // [16][1024][18]
    const float* wt  = (const float*)d_in[2];   // [256][256][3][3]
    float* out = (float*)d_out;                 // [16][256][32][32]

    unsigned short* wbf  = (unsigned short*)d_ws;                        // 256*2304*2 = 1179648 B
    unsigned short* valt = (unsigned short*)((char*)d_ws + 1179648);     // 16*1024*2304*2 = 75497472 B

    wconv_kernel<<<576, 256, 0, stream>>>((const float4*)wt, (uint2*)wbf);
    sample_kernel<<<dim3(32, 16), 256, 0, stream>>>(x, off, valt);
    gemm_kernel<<<dim3(4, 8, 16), 256, 0, stream>>>(wbf, valt, out);
}

// Round 3
// 129.654 us; speedup vs baseline: 2.1425x; 1.1804x over previous
//
#include <hip/hip_runtime.h>

// Problem constants
#define NB   16
#define CIN  256
#define COUT 256
#define HH   32
#define WW   32
#define HW   1024           // 32*32
#define KK   9
#define CK   2304           // CIN*KK  (ordered k*256 + c, tap-major)

typedef __bf16 bf16x8 __attribute__((ext_vector_type(8)));
typedef float  f32x4  __attribute__((ext_vector_type(4)));

__device__ __forceinline__ unsigned short f2bf(float f) {
    unsigned int u = __float_as_uint(f);
    u += 0x7FFFu + ((u >> 16) & 1u);          // round-nearest-even
    return (unsigned short)(u >> 16);
}
__device__ __forceinline__ float bfhi(unsigned int u) {   // high bf16 -> f32
    return __uint_as_float(u & 0xFFFF0000u);
}
__device__ __forceinline__ float bflo(unsigned int u) {   // low bf16 -> f32
    return __uint_as_float(u << 16);
}

typedef const __attribute__((address_space(1))) void* gas_ptr;
typedef __attribute__((address_space(3))) void* las_ptr;

__device__ __forceinline__ void async16(const void* g, void* l) {
    __builtin_amdgcn_global_load_lds((gas_ptr)g, (las_ptr)l, 16, 0, 0);
}

// ---------------------------------------------------------------- wconv ----
// weight fp32 [O][C][3][3] -> bf16 [O][k*256+c]  (tap-major)
__global__ __launch_bounds__(256) void wconv_kernel(const float* __restrict__ w,
                                                    unsigned short* __restrict__ wbf) {
    __shared__ float ls[CK];
    const int o = blockIdx.x;
    const float* wo = w + (size_t)o * CK;
#pragma unroll
    for (int i = threadIdx.x; i < CK; i += 256) ls[i] = wo[i];
    __syncthreads();
    unsigned short* dst = wbf + (size_t)o * CK;
#pragma unroll
    for (int i = threadIdx.x; i < CK; i += 256) {
        int k = i >> 8, c = i & 255;
        dst[i] = f2bf(ls[c * KK + k]);        // bank stride 9: conflict-free
    }
}

// ------------------------------------------------------------------- xt ----
// x fp32 [n][c][hw] -> xtb bf16 [n][hw][c]   (64x64 LDS tile transpose)
__global__ __launch_bounds__(256) void xt_kernel(const float* __restrict__ x,
                                                 unsigned short* __restrict__ xtb) {
    __shared__ float ls[64][65];
    const int c0  = blockIdx.x * 64;
    const int hw0 = blockIdx.y * 64;
    const int n   = blockIdx.z;
    const int t   = threadIdx.x;
    {
        int c = t >> 2, q = t & 3;
        const float* base = x + ((size_t)(n * CIN + c0 + c)) * HW + hw0 + q * 16;
#pragma unroll
        for (int j = 0; j < 16; ++j) ls[c][q * 16 + j] = base[j];
    }
    __syncthreads();
    {
        int hw = t >> 2, seg = (t & 3) * 16;
        unsigned int dw[8];
#pragma unroll
        for (int j = 0; j < 8; ++j) {
            float f0 = ls[seg + 2 * j][hw];
            float f1 = ls[seg + 2 * j + 1][hw];
            dw[j] = (unsigned)f2bf(f0) | ((unsigned)f2bf(f1) << 16);
        }
        uint4* dst = (uint4*)(xtb + ((size_t)(n * HW + hw0 + hw)) * CIN + c0 + seg);
        dst[0] = *(uint4*)&dw[0];
        dst[1] = *(uint4*)&dw[4];
    }
}

// --------------------------------------------------------------- sample ----
// valt[n][hw][k*256+c] bf16. One wave per 8 (hw,tap) pairs; for each pair all
// 64 lanes cooperatively sample 256 channels (4 bf16 each) from xtb rows.
__global__ __launch_bounds__(256) void sample_kernel(const unsigned short* __restrict__ xtb,
                                                     const float* __restrict__ off,
                                                     unsigned short* __restrict__ valt) {
    const int wv   = threadIdx.x >> 6;
    const int lane = threadIdx.x & 63;
    const unsigned pbase = blockIdx.x * 32 + wv * 8;

#pragma unroll
    for (int i = 0; i < 8; ++i) {
        unsigned p = pbase + i;
        unsigned k = p % 9u;
        unsigned rest = p / 9u;
        unsigned hw = rest & 1023u;
        unsigned n  = rest >> 10;
        int h = (int)(hw >> 5), w = (int)(hw & 31);

        const float2* op2 = (const float2*)(off + ((size_t)(n * HW + hw)) * (2 * KK));
        float2 o = op2[k];
        float py = (float)(h + (int)(k / 3) - 1) + o.x;
        float px = (float)(w + (int)(k % 3) - 1) + o.y;
        float y0f = floorf(py), x0f = floorf(px);
        float ly = py - y0f, lx = px - x0f;
        int y0 = (int)y0f, x0 = (int)x0f;

        float wgt[4];
        int   ridx[4];
#pragma unroll
        for (int c2 = 0; c2 < 4; ++c2) {
            int yy = y0 + (c2 >> 1);
            int xx = x0 + (c2 & 1);
            float wy = (c2 >> 1) ? ly : 1.0f - ly;
            float wx = (c2 & 1) ? lx : 1.0f - lx;
            bool v = (yy >= 0) && (yy < HH) && (xx >= 0) && (xx < WW);
            wgt[c2] = v ? wy * wx : 0.0f;
            int yc = yy < 0 ? 0 : (yy > HH - 1 ? HH - 1 : yy);
            int xc = xx < 0 ? 0 : (xx > WW - 1 ? WW - 1 : xx);
            ridx[c2] = yc * WW + xc;
        }

        const uint2* base = (const uint2*)(xtb + (size_t)n * HW * CIN);
        uint2 d0 = base[(size_t)ridx[0] * 64 + lane];
        uint2 d1 = base[(size_t)ridx[1] * 64 + lane];
        uint2 d2 = base[(size_t)ridx[2] * 64 + lane];
        uint2 d3 = base[(size_t)ridx[3] * 64 + lane];

        float r0 = wgt[0] * bflo(d0.x) + wgt[1] * bflo(d1.x) + wgt[2] * bflo(d2.x) + wgt[3] * bflo(d3.x);
        float r1 = wgt[0] * bfhi(d0.x) + wgt[1] * bfhi(d1.x) + wgt[2] * bfhi(d2.x) + wgt[3] * bfhi(d3.x);
        float r2 = wgt[0] * bflo(d0.y) + wgt[1] * bflo(d1.y) + wgt[2] * bflo(d2.y) + wgt[3] * bflo(d3.y);
        float r3 = wgt[0] * bfhi(d0.y) + wgt[1] * bfhi(d1.y) + wgt[2] * bfhi(d2.y) + wgt[3] * bfhi(d3.y);

        uint2 outv;
        outv.x = (unsigned)f2bf(r0) | ((unsigned)f2bf(r1) << 16);
        outv.y = (unsigned)f2bf(r2) | ((unsigned)f2bf(r3) << 16);
        uint2* dst = (uint2*)(valt);
        dst[(size_t)(n * HW + hw) * 576 + k * 64 + lane] = outv;
    }
}

// ----------------------------------------------------------------- gemm ----
// Per image: out[O][HW] = wbf[O][CK] * valt[HW][CK]^T
// BM=64, BN=64, BK=64. 2x2 waves, wave tile 32x32. XOR-swizzled LDS rows
// (chunk ^= row&7, applied via staging source permutation so global_load_lds
// lane-linear dest still works). Grid 1024 1-D, XCD-aware decode: the 4
// o-blocks sharing a B tile get ids {q,q+8,q+16,q+24} -> same XCD -> L2 reuse.
__global__ __launch_bounds__(256, 4) void gemm_kernel(const unsigned short* __restrict__ wbf,
                                                      const unsigned short* __restrict__ valt,
                                                      float* __restrict__ out) {
    __shared__ unsigned short As[64 * 64];    // 8 KB, rows of 128 B
    __shared__ unsigned short Bs[64 * 64];

    const int tid  = threadIdx.x;
    const int wv   = tid >> 6;
    const int lane = tid & 63;
    const int quad = lane >> 4;
    const int l15  = lane & 15;
    const int wm   = wv & 1;
    const int wn   = wv >> 1;

    const int id = blockIdx.x;
    const int g  = id >> 5;
    const int r  = id & 31;
    const int o0 = (r >> 3) * 64;
    const int p  = g * 8 + (r & 7);           // 0..255
    const int hw0 = (p & 15) * 64;
    const int n   = p >> 4;

    // staging: lane -> row srow=lane>>3, source chunk = (lane&7) ^ (srow&7)
    const int srow   = lane >> 3;
    const int schunk = (lane & 7) ^ (srow & 7);

    const unsigned short* Ag = wbf + (size_t)o0 * CK;
    const unsigned short* Bg = valt + ((size_t)n * HW + hw0) * CK;

    f32x4 acc[2][2] = {};

    for (int ck0 = 0; ck0 < CK; ck0 += 64) {
        __syncthreads();
#pragma unroll
        for (int j = 0; j < 2; ++j) {
            int rb = wv * 16 + j * 8;         // 8 rows per instr
            async16(Ag + (size_t)(rb + srow) * CK + ck0 + schunk * 8, &As[rb * 64]);
            async16(Bg + (size_t)(rb + srow) * CK + ck0 + schunk * 8, &Bs[rb * 64]);
        }
        __syncthreads();

        bf16x8 af[2][2], bfr[2][2];
#pragma unroll
        for (int mi = 0; mi < 2; ++mi)
#pragma unroll
            for (int hh = 0; hh < 2; ++hh) {
                int row = wm * 32 + mi * 16 + l15;
                int ch  = (hh * 4 + quad) ^ (row & 7);
                af[mi][hh] = *(const bf16x8*)&As[row * 64 + ch * 8];
            }
#pragma unroll
        for (int ni = 0; ni < 2; ++ni)
#pragma unroll
            for (int hh = 0; hh < 2; ++hh) {
                int row = wn * 32 + ni * 16 + l15;
                int ch  = (hh * 4 + quad) ^ (row & 7);
                bfr[ni][hh] = *(const bf16x8*)&Bs[row * 64 + ch * 8];
            }
#pragma unroll
        for (int mi = 0; mi < 2; ++mi)
#pragma unroll
            for (int ni = 0; ni < 2; ++ni) {
                acc[mi][ni] = __builtin_amdgcn_mfma_f32_16x16x32_bf16(af[mi][0], bfr[ni][0], acc[mi][ni], 0, 0, 0);
                acc[mi][ni] = __builtin_amdgcn_mfma_f32_16x16x32_bf16(af[mi][1], bfr[ni][1], acc[mi][ni], 0, 0, 0);
            }
    }

    // epilogue: D layout col = lane&15, row = quad*4 + reg
    float* opnt = out + ((size_t)n * COUT + o0) * HW + hw0;
#pragma unroll
    for (int mi = 0; mi < 2; ++mi)
#pragma unroll
        for (int ni = 0; ni < 2; ++ni) {
            int col = wn * 32 + ni * 16 + l15;
#pragma unroll
            for (int rr = 0; rr < 4; ++rr) {
                int row = wm * 32 + mi * 16 + quad * 4 + rr;
                opnt[(size_t)row * HW + col] = acc[mi][ni][rr];
            }
        }
}

// --------------------------------------------------------------- launch ----
extern "C" void kernel_launch(void* const* d_in, const int* in_sizes, int n_in,
                              void* d_out, int out_size, void* d_ws, size_t ws_size,
                              hipStream_t stream) {
    const float* x   = (const float*)d_in[0];   // [16][256][32][32]
    const float* off = (const float*)d_in[1];   // [16][1024][18]
    const float* wt  = (const float*)d_in[2];   // [256][256][3][3]
    float* out = (float*)d_out;                 // [16][256][32][32]

    unsigned short* wbf  = (unsigned short*)d_ws;                        // 1179648 B
    unsigned short* xtb  = (unsigned short*)((char*)d_ws + 1179648);     // 8388608 B
    unsigned short* valt = (unsigned short*)((char*)d_ws + 9568256);     // 75497472 B

    wconv_kernel<<<256, 256, 0, stream>>>(wt, wbf);
    xt_kernel<<<dim3(4, 16, 16), 256, 0, stream>>>(x, xtb);
    sample_kernel<<<4608, 256, 0, stream>>>(xtb, off, valt);
    gemm_kernel<<<1024, 256, 0, stream>>>(wbf, valt, out);
}